// Round 6
// baseline (92.727 us; speedup 1.0000x reference)
//
#include <hip/hip_runtime.h>
#include <math.h>

typedef unsigned short ushort_t;
typedef short short8 __attribute__((ext_vector_type(8)));
typedef float floatx4 __attribute__((ext_vector_type(4)));

#define MFMA16(a,b,c) __builtin_amdgcn_mfma_f32_16x16x32_bf16((a),(b),(c),0,0,0)

// ---------------- ws layout (ushort/bf16 elements) ----------------
#define PK_STFT 0          // 17ct x 8kk          = 69632   B[k=0..255][n=0..271], n>=258 -> 0
#define PK_W1   69632      // 3tap x (8ct x 5kk)  = 61440   B[f=0..159][c], f>=129 -> 0
#define PK_W2   131072     // 4ct x 12kk          = 24576   B[k*128+f][c]
#define PK_W3   155648     // 4ct x 6kk           = 12288   B[k*64+f][c]
#define PK_W4   167936     // 8ct x 2kk           = 8192    B[f=0..63][c]  (tap k=1 only)
#define PK_LSTM 176128     // 32ct x 8kk          = 131072  B[k=0..255][n], k<128: w_ih, else w_hh
#define OFF_FEAT 307200    // [B][128] bf16

__device__ __forceinline__ ushort_t f2bf(float f){
    unsigned int u = __float_as_uint(f);
    u += 0x7fffu + ((u >> 16) & 1u);
    return (ushort_t)(u >> 16);
}
__device__ __forceinline__ float bf2f(ushort_t h){
    return __uint_as_float(((unsigned int)h) << 16);
}
__device__ __forceinline__ unsigned int pack2(float a, float b){
    return (unsigned int)f2bf(a) | ((unsigned int)f2bf(b) << 16);
}
__device__ __forceinline__ float fsig(float v){
    return __builtin_amdgcn_rcpf(1.f + __builtin_amdgcn_exp2f(-1.44269504f * v));
}
__device__ __forceinline__ float ftanh(float v){
    return 2.f * __builtin_amdgcn_rcpf(1.f + __builtin_amdgcn_exp2f(-2.88539008f * v)) - 1.f;
}

// ---------------- prep: pack weights to fragment-linear bf16 ----------------
__global__ __launch_bounds__(256) void prep_kernel(
    const float* __restrict__ stft_w, const float* __restrict__ w1,
    const float* __restrict__ w2, const float* __restrict__ w3,
    const float* __restrict__ w4, const float* __restrict__ wih,
    const float* __restrict__ whh, ushort_t* __restrict__ wp)
{
    int i = blockIdx.x * 256 + threadIdx.x;
    if (i >= 307200) return;
    float val = 0.f;
    if (i < PK_W1) {                                  // STFT
        int frag = i >> 9, rr = i & 511, l = rr >> 3, j = rr & 7;
        int ct = frag >> 3, kk = frag & 7;
        int kd = kk * 32 + ((l >> 4) << 3) + j;
        int n = ct * 16 + (l & 15);
        val = (n < 258) ? stft_w[n * 256 + kd] : 0.f;
    } else if (i < PK_W2) {                           // W1 (tap-major)
        int r = i - PK_W1;
        int tap = r / 20480; r -= tap * 20480;
        int frag = r >> 9, rr = r & 511, l = rr >> 3, j = rr & 7;
        int ct = frag / 5, kk = frag - ct * 5;
        int kd = kk * 32 + ((l >> 4) << 3) + j;
        int c = ct * 16 + (l & 15);
        val = (kd < 129) ? w1[c * 387 + kd * 3 + tap] : 0.f;
    } else if (i < PK_W3) {                           // W2
        int r = i - PK_W2;
        int frag = r >> 9, rr = r & 511, l = rr >> 3, j = rr & 7;
        int ct = frag / 12, kk = frag - ct * 12;
        int kd = kk * 32 + ((l >> 4) << 3) + j;
        int k = kd >> 7, f = kd & 127;
        int c = ct * 16 + (l & 15);
        val = w2[c * 384 + f * 3 + k];
    } else if (i < PK_W4) {                           // W3
        int r = i - PK_W3;
        int frag = r >> 9, rr = r & 511, l = rr >> 3, j = rr & 7;
        int ct = frag / 6, kk = frag - ct * 6;
        int kd = kk * 32 + ((l >> 4) << 3) + j;
        int k = kd >> 6, f = kd & 63;
        int c = ct * 16 + (l & 15);
        val = w3[c * 192 + f * 3 + k];
    } else if (i < PK_LSTM) {                         // W4 (center tap only)
        int r = i - PK_W4;
        int frag = r >> 9, rr = r & 511, l = rr >> 3, j = rr & 7;
        int ct = frag >> 1, kk = frag & 1;
        int kd = kk * 32 + ((l >> 4) << 3) + j;
        int c = ct * 16 + (l & 15);
        val = w4[c * 192 + kd * 3 + 1];
    } else {                                          // LSTM [feat|h] -> 512 gates
        int r = i - PK_LSTM;
        int frag = r >> 9, rr = r & 511, l = rr >> 3, j = rr & 7;
        int ct = frag >> 3, kk = frag & 7;
        int kd = kk * 32 + ((l >> 4) << 3) + j;
        int n = ct * 16 + (l & 15);
        val = (kd < 128) ? wih[n * 128 + kd] : whh[n * 128 + (kd - 128)];
    }
    wp[i] = f2bf(val);
}

// ---------------- fused feat: STFT + mag + conv1..4 ----------------
// 16 batches/block, 256 thr (4 waves), ~51 KB LDS -> 3 blocks/CU.
__global__ __launch_bounds__(256, 3) void feat_kernel(
    const float* __restrict__ x, const ushort_t* __restrict__ wp,
    const float* __restrict__ b1, const float* __restrict__ b2,
    const float* __restrict__ b3, const float* __restrict__ b4,
    ushort_t* __restrict__ featg)
{
    __shared__ ushort_t A[12672];   // xs[48][264] -> s[48][264] -> h1h[16][5][136] -> h3s[16][72]
    __shared__ ushort_t Bb[13440];  // mag[16][5][168] -> h2h[16][3][72] -> featbuf[16][128]

    const int tid = threadIdx.x, lane = tid & 63, wid = tid >> 6;
    const int l15 = lane & 15, lk = lane >> 4;
    const size_t b0 = (size_t)blockIdx.x * 16;

    // ---- P0: zero Bb (mag halos), stage x -> A (im2col) ----
    for (int i = tid; i < 6720; i += 256) ((unsigned int*)Bb)[i] = 0u;
    {
        const float4* xg = (const float4*)(x + b0 * 512);
#pragma unroll
        for (int i = 0; i < 8; ++i) {
            int idx4 = tid + i * 256;
            float4 v = xg[idx4];
            int b = idx4 >> 7, c4 = idx4 & 127;
            int si = c4 * 4, t1 = si >> 7;
            unsigned int u0 = pack2(v.x, v.y), u1 = pack2(v.z, v.w);
            if (t1 < 3) {
                ushort_t* p = &A[(b * 3 + t1) * 264 + (si & 127)];
                *(unsigned int*)p = u0; *(unsigned int*)(p + 2) = u1;
            }
            if (t1 >= 1) {
                ushort_t* p = &A[(b * 3 + t1 - 1) * 264 + (si & 127) + 128];
                *(unsigned int*)p = u0; *(unsigned int*)(p + 2) = u1;
            }
        }
    }
    __syncthreads();

    // ---- P1: STFT MFMA -> regs. M=48(3rt) N=272(17ct) K=256(8kk) ----
    floatx4 accs[5][3];
#pragma unroll
    for (int ci = 0; ci < 5; ++ci)
#pragma unroll
        for (int rt = 0; rt < 3; ++rt) accs[ci][rt] = (floatx4){0.f, 0.f, 0.f, 0.f};
#pragma unroll
    for (int ci = 0; ci < 5; ++ci) {
        int ct = wid + ci * 4;
        if (ct < 17) {
            short8 bfrag[8];
            const short8* bp = (const short8*)(wp + PK_STFT) + (size_t)(ct * 8) * 64 + lane;
#pragma unroll
            for (int kk = 0; kk < 8; ++kk) bfrag[kk] = bp[kk * 64];
#pragma unroll
            for (int rt = 0; rt < 3; ++rt) {
                const ushort_t* abase = &A[(rt * 16 + l15) * 264 + lk * 8];
                floatx4 a = accs[ci][rt];
#pragma unroll
                for (int kk = 0; kk < 8; ++kk)
                    a = MFMA16(*(const short8*)(abase + kk * 32), bfrag[kk], a);
                accs[ci][rt] = a;
            }
        }
    }
    __syncthreads();

    // ---- P2: write s over xs (alias) ----
#pragma unroll
    for (int ci = 0; ci < 5; ++ci) {
        int ct = wid + ci * 4;
        if (ct < 17) {
            int col = ct * 16 + l15;
            if (col < 258) {
#pragma unroll
                for (int rt = 0; rt < 3; ++rt) {
                    int r0 = rt * 16 + lk * 4;
#pragma unroll
                    for (int jj = 0; jj < 4; ++jj)
                        A[(r0 + jj) * 264 + col] = f2bf(accs[ci][rt][jj]);
                }
            }
        }
    }
    __syncthreads();

    // ---- P3: magnitude -> mag[16][5][168] in Bb (halos stay P0-zero) ----
    for (int idx = tid; idx < 6192; idx += 256) {
        int bt = idx / 129, f = idx - bt * 129;
        float re = bf2f(A[bt * 264 + f]);
        float im = bf2f(A[bt * 264 + 129 + f]);
        int b = bt / 3, t = bt - b * 3;
        Bb[b * 840 + (1 + t) * 168 + f] = f2bf(sqrtf(re * re + im * im));
    }
    __syncthreads();

    // ---- P4: conv1 MFMA -> regs. M=48(3rt) N=128(8ct) K=160x3taps ----
    floatx4 acc1[2][3];
#pragma unroll
    for (int ci = 0; ci < 2; ++ci)
#pragma unroll
        for (int rt = 0; rt < 3; ++rt) acc1[ci][rt] = (floatx4){0.f, 0.f, 0.f, 0.f};
#pragma unroll
    for (int ci = 0; ci < 2; ++ci) {
        int ct = wid + ci * 4;
        short8 bfrag[15];
#pragma unroll
        for (int tap = 0; tap < 3; ++tap)
#pragma unroll
            for (int kk = 0; kk < 5; ++kk)
                bfrag[tap * 5 + kk] = ((const short8*)(wp + PK_W1))[(size_t)(tap * 40 + ct * 5 + kk) * 64 + lane];
#pragma unroll
        for (int rt = 0; rt < 3; ++rt) {
            int obt = rt * 16 + l15;
            int b = obt / 3, t = obt - b * 3;
#pragma unroll
            for (int tap = 0; tap < 3; ++tap) {
                const ushort_t* abase = &Bb[(b * 5 + t + tap) * 168 + lk * 8];
#pragma unroll
                for (int kk = 0; kk < 5; ++kk)
                    acc1[ci][rt] = MFMA16(*(const short8*)(abase + kk * 32), bfrag[tap * 5 + kk], acc1[ci][rt]);
            }
        }
    }
    __syncthreads();

    // ---- P5: h1h -> A (halos + data); zero h2h t''=0 rows in Bb ----
    {
        unsigned int* h1z = (unsigned int*)A;
        for (int i = tid; i < 2176; i += 256) {
            int bb = i / 136, r = i - bb * 136;
            int tp = (r < 68) ? 0 : 4, f2 = (r < 68) ? r : r - 68;
            h1z[(bb * 5 + tp) * 68 + f2] = 0u;
        }
        for (int i = tid; i < 576; i += 256) {
            int bb = i / 36, f2 = i - bb * 36;
            ((unsigned int*)Bb)[bb * 108 + f2] = 0u;
        }
#pragma unroll
        for (int ci = 0; ci < 2; ++ci) {
            int ct = wid + ci * 4, col = ct * 16 + l15;
            float bias = b1[col];
#pragma unroll
            for (int rt = 0; rt < 3; ++rt)
#pragma unroll
                for (int jj = 0; jj < 4; ++jj) {
                    int obt = rt * 16 + lk * 4 + jj;
                    int b = obt / 3, t = obt - b * 3;
                    A[(b * 5 + t + 1) * 136 + col] = f2bf(fmaxf(acc1[ci][rt][jj] + bias, 0.f));
                }
        }
    }
    __syncthreads();

    // ---- P6: conv2. M=32(2rt) N=64(4ct) K=384(12kk); read A(h1h), write h2h -> Bb ----
    {
        int ct = wid;
        short8 bfrag[12];
#pragma unroll
        for (int kk = 0; kk < 12; ++kk)
            bfrag[kk] = ((const short8*)(wp + PK_W2))[(size_t)(ct * 12 + kk) * 64 + lane];
        int col = ct * 16 + l15;
        float bias = b2[col];
#pragma unroll
        for (int rt = 0; rt < 2; ++rt) {
            floatx4 acc = {0.f, 0.f, 0.f, 0.f};
            int orow = rt * 16 + l15;
            int b = orow >> 1, t2 = orow & 1;
#pragma unroll
            for (int kk = 0; kk < 12; ++kk) {
                int k = kk >> 2, f = (kk & 3) * 32 + lk * 8;
                short8 af = *(const short8*)(&A[(b * 5 + 2 * t2 + k) * 136 + f]);
                acc = MFMA16(af, bfrag[kk], acc);
            }
#pragma unroll
            for (int jj = 0; jj < 4; ++jj) {
                int orw = rt * 16 + lk * 4 + jj;
                int bb = orw >> 1, tt = orw & 1;
                Bb[(bb * 3 + 1 + tt) * 72 + col] = f2bf(fmaxf(acc[jj] + bias, 0.f));
            }
        }
    }
    __syncthreads();

    // ---- P7: conv3. M=16 N=64(4ct) K=192(6kk); read Bb(h2h), write h3s -> A ----
    {
        int ct = wid;
        short8 bfrag[6];
#pragma unroll
        for (int kk = 0; kk < 6; ++kk)
            bfrag[kk] = ((const short8*)(wp + PK_W3))[(size_t)(ct * 6 + kk) * 64 + lane];
        int col = ct * 16 + l15;
        float bias = b3[col];
        floatx4 acc = {0.f, 0.f, 0.f, 0.f};
        int b = l15;
#pragma unroll
        for (int kk = 0; kk < 6; ++kk) {
            int k = kk >> 1, f = (kk & 1) * 32 + lk * 8;
            short8 af = *(const short8*)(&Bb[(b * 3 + k) * 72 + f]);
            acc = MFMA16(af, bfrag[kk], acc);
        }
#pragma unroll
        for (int jj = 0; jj < 4; ++jj)
            A[(lk * 4 + jj) * 72 + col] = f2bf(fmaxf(acc[jj] + bias, 0.f));
    }
    __syncthreads();

    // ---- P8: conv4. M=16 N=128(8ct) K=64(2kk); read A(h3s), stage feat -> Bb, store ----
    {
        ushort_t* fbuf = Bb;                 // [16][128], h2h dead after P7 barrier
#pragma unroll
        for (int ci = 0; ci < 2; ++ci) {
            int ct = wid + ci * 4;
            short8 bf0 = ((const short8*)(wp + PK_W4))[(size_t)(ct * 2 + 0) * 64 + lane];
            short8 bf1 = ((const short8*)(wp + PK_W4))[(size_t)(ct * 2 + 1) * 64 + lane];
            int col = ct * 16 + l15;
            float bias = b4[col];
            floatx4 acc = {0.f, 0.f, 0.f, 0.f};
            int b = l15;
            short8 a0 = *(const short8*)(&A[b * 72 + lk * 8]);
            short8 a1 = *(const short8*)(&A[b * 72 + 32 + lk * 8]);
            acc = MFMA16(a0, bf0, acc);
            acc = MFMA16(a1, bf1, acc);
#pragma unroll
            for (int jj = 0; jj < 4; ++jj)
                fbuf[(lk * 4 + jj) * 128 + col] = f2bf(fmaxf(acc[jj] + bias, 0.f));
        }
        __syncthreads();
        unsigned int* fgd = (unsigned int*)(featg + b0 * 128);
        const unsigned int* fls = (const unsigned int*)fbuf;
#pragma unroll
        for (int k = 0; k < 4; ++k) fgd[tid + k * 256] = fls[tid + k * 256];
    }
}

// ---------------- K3: LSTM gates (MFMA) + cell + head ----------------
// 32 batches/block, 512 thr (8 waves). M=32(2rt) N=512(32ct) K=256(8kk).
__global__ __launch_bounds__(512, 6) void lstm_kernel(
    const ushort_t* __restrict__ featg, const float* __restrict__ state,
    const ushort_t* __restrict__ wp, const float* __restrict__ bih,
    const float* __restrict__ bhh, const float* __restrict__ fw,
    const float* __restrict__ fbp, float* __restrict__ out, int B)
{
    __shared__ ushort_t inc[32 * 264];   // A-operand; later aliased as hn staging [32][132] f32
    __shared__ float cpl[32 * 132];      // c_prev staged; later cn staging (in-place)
    __shared__ float red[256];
    const int tid = threadIdx.x, lane = tid & 63, wid = tid >> 6;
    const int l15 = lane & 15, lk = lane >> 4;
    const size_t b0 = (size_t)blockIdx.x * 32;
    const int cc = wid * 16 + l15;
    const float* cprev = state + (size_t)B * 128;

    // ---- coalesced staging: feat, h_prev (bf16-packed), c_prev ----
    {
        const unsigned int* fg = (const unsigned int*)(featg + b0 * 128);
        unsigned int* ip = (unsigned int*)inc;
        for (int i = tid; i < 2048; i += 512) {
            int bb = i >> 6, f2 = i & 63;
            ip[bb * 132 + f2] = fg[i];
        }
        const float2* hp2 = (const float2*)(state + b0 * 128);
        for (int i = tid; i < 2048; i += 512) {
            int bb = i >> 6, c2 = i & 63;
            float2 v = hp2[i];
            ip[bb * 132 + 64 + c2] = pack2(v.x, v.y);
        }
        const float* cg = cprev + b0 * 128;
        for (int i = tid; i < 4096; i += 512) {
            int bb = i >> 7, c = i & 127;
            cpl[bb * 132 + c] = cg[i];
        }
    }
    __syncthreads();

    // ---- gates MFMA ----
    floatx4 acc[4][2];
#pragma unroll
    for (int ci = 0; ci < 4; ++ci) {
        int ct = wid + ci * 8;
        short8 bfrag[8];
#pragma unroll
        for (int kk = 0; kk < 8; ++kk)
            bfrag[kk] = ((const short8*)(wp + PK_LSTM))[(size_t)(ct * 8 + kk) * 64 + lane];
#pragma unroll
        for (int rt = 0; rt < 2; ++rt) {
            const ushort_t* abase = &inc[(rt * 16 + l15) * 264 + lk * 8];
            floatx4 a = {0.f, 0.f, 0.f, 0.f};
#pragma unroll
            for (int kk = 0; kk < 8; ++kk) {
                short8 af = *(const short8*)(abase + kk * 32);
                a = MFMA16(af, bfrag[kk], a);
            }
            acc[ci][rt] = a;
        }
    }
    __syncthreads();   // inc A-reads complete before hn staging aliases it

    // ---- cell update into LDS staging + head partials ----
    float* hsl = (float*)inc;            // [32][132] f32
    float* csl = cpl;                    // in-place (owner-thread RAW only)
    const float bi = bih[cc] + bhh[cc];
    const float bf_ = bih[cc + 128] + bhh[cc + 128];
    const float bg = bih[cc + 256] + bhh[cc + 256];
    const float bo = bih[cc + 384] + bhh[cc + 384];
    const float fwv = fw[cc];
    float ph[2][4];
#pragma unroll
    for (int rt = 0; rt < 2; ++rt)
#pragma unroll
        for (int jj = 0; jj < 4; ++jj) {
            int row = rt * 16 + lk * 4 + jj;
            float gi = acc[0][rt][jj] + bi;
            float gf = acc[1][rt][jj] + bf_;
            float gg = acc[2][rt][jj] + bg;
            float go = acc[3][rt][jj] + bo;
            float cn = fsig(gf) * cpl[row * 132 + cc] + fsig(gi) * ftanh(gg);
            float hn = fsig(go) * ftanh(cn);
            hsl[row * 132 + cc] = hn;
            csl[row * 132 + cc] = cn;
            ph[rt][jj] = fmaxf(hn, 0.f) * fwv;
        }

#pragma unroll
    for (int rt = 0; rt < 2; ++rt)
#pragma unroll
        for (int jj = 0; jj < 4; ++jj) {
            float v = ph[rt][jj];
            v += __shfl_xor(v, 1, 64);
            v += __shfl_xor(v, 2, 64);
            v += __shfl_xor(v, 4, 64);
            v += __shfl_xor(v, 8, 64);
            if (l15 == 0) red[wid * 32 + rt * 16 + lk * 4 + jj] = v;
        }
    __syncthreads();

    // ---- coalesced output streams ----
    {
        float* outh = out + B + b0 * 128;
        float* outc = out + B + (size_t)B * 128 + b0 * 128;
        for (int i = tid; i < 4096; i += 512) {
            int bb = i >> 7, c = i & 127;
            outh[i] = hsl[bb * 132 + c];
            outc[i] = csl[bb * 132 + c];
        }
    }
    if (tid < 32) {
        float v = 0.f;
#pragma unroll
        for (int w = 0; w < 8; ++w) v += red[w * 32 + tid];
        out[b0 + tid] = fsig(v + fbp[0]);
    }
}

extern "C" void kernel_launch(void* const* d_in, const int* in_sizes, int n_in,
                              void* d_out, int out_size, void* d_ws, size_t ws_size,
                              hipStream_t stream) {
    const float* x      = (const float*)d_in[0];
    const float* state  = (const float*)d_in[1];
    const float* stft_w = (const float*)d_in[2];
    const float* w1     = (const float*)d_in[3];
    const float* b1     = (const float*)d_in[4];
    const float* w2     = (const float*)d_in[5];
    const float* b2     = (const float*)d_in[6];
    const float* w3     = (const float*)d_in[7];
    const float* b3     = (const float*)d_in[8];
    const float* w4     = (const float*)d_in[9];
    const float* b4     = (const float*)d_in[10];
    const float* wih    = (const float*)d_in[11];
    const float* whh    = (const float*)d_in[12];
    const float* bih    = (const float*)d_in[13];
    const float* bhh    = (const float*)d_in[14];
    const float* fw     = (const float*)d_in[15];
    const float* fbp    = (const float*)d_in[16];

    ushort_t* wp = (ushort_t*)d_ws;
    const int B = in_sizes[0] / 512;   // 16384

    prep_kernel<<<1200, 256, 0, stream>>>(stft_w, w1, w2, w3, w4, wih, whh, wp);
    feat_kernel<<<B / 16, 256, 0, stream>>>(x, wp, b1, b2, b3, b4, wp + OFF_FEAT);
    lstm_kernel<<<B / 32, 512, 0, stream>>>(wp + OFF_FEAT, state, wp, bih, bhh, fw, fbp,
                                            (float*)d_out, B);
}

// Round 7
// 77.626 us; speedup vs baseline: 1.1945x; 1.1945x over previous
//
#include <hip/hip_runtime.h>
#include <math.h>

typedef unsigned short ushort_t;
typedef short short8 __attribute__((ext_vector_type(8)));
typedef float floatx4 __attribute__((ext_vector_type(4)));

#define MFMA16(a,b,c) __builtin_amdgcn_mfma_f32_16x16x32_bf16((a),(b),(c),0,0,0)

// ---------------- ws layout (ushort/bf16 elements) ----------------
#define PK_STFT 0          // 17ct x 8kk          = 69632   B[k=0..255][n=0..271], n>=258 -> 0
#define PK_W1   69632      // 3tap x (8ct x 5kk)  = 61440   B[f=0..159][c], f>=129 -> 0
#define PK_W2   131072     // 4ct x 12kk          = 24576   B[k*128+f][c]
#define PK_W3   155648     // 4ct x 6kk           = 12288   B[k*64+f][c]
#define PK_W4   167936     // 8ct x 2kk           = 8192    B[f=0..63][c]  (tap k=1 only)
#define PK_LSTM 176128     // 32ct x 8kk          = 131072  B[k=0..255][n], k<128: w_ih, else w_hh
#define OFF_MAG 307200     // [B][3][160] bf16
#define OFF_FEAT 8171520   // [B][128] bf16

__device__ __forceinline__ ushort_t f2bf(float f){
    unsigned int u = __float_as_uint(f);
    u += 0x7fffu + ((u >> 16) & 1u);
    return (ushort_t)(u >> 16);
}
__device__ __forceinline__ float bf2f(ushort_t h){
    return __uint_as_float(((unsigned int)h) << 16);
}
__device__ __forceinline__ unsigned int pack2(float a, float b){
    return (unsigned int)f2bf(a) | ((unsigned int)f2bf(b) << 16);
}
__device__ __forceinline__ float fsig(float v){
    return __builtin_amdgcn_rcpf(1.f + __builtin_amdgcn_exp2f(-1.44269504f * v));
}
__device__ __forceinline__ float ftanh(float v){
    return 2.f * __builtin_amdgcn_rcpf(1.f + __builtin_amdgcn_exp2f(-2.88539008f * v)) - 1.f;
}

// ---------------- prep: pack weights to fragment-linear bf16 ----------------
__global__ __launch_bounds__(256) void prep_kernel(
    const float* __restrict__ stft_w, const float* __restrict__ w1,
    const float* __restrict__ w2, const float* __restrict__ w3,
    const float* __restrict__ w4, const float* __restrict__ wih,
    const float* __restrict__ whh, ushort_t* __restrict__ wp)
{
    int i = blockIdx.x * 256 + threadIdx.x;
    if (i >= 307200) return;
    float val = 0.f;
    if (i < PK_W1) {                                  // STFT
        int frag = i >> 9, rr = i & 511, l = rr >> 3, j = rr & 7;
        int ct = frag >> 3, kk = frag & 7;
        int kd = kk * 32 + ((l >> 4) << 3) + j;
        int n = ct * 16 + (l & 15);
        val = (n < 258) ? stft_w[n * 256 + kd] : 0.f;
    } else if (i < PK_W2) {                           // W1 (tap-major)
        int r = i - PK_W1;
        int tap = r / 20480; r -= tap * 20480;
        int frag = r >> 9, rr = r & 511, l = rr >> 3, j = rr & 7;
        int ct = frag / 5, kk = frag - ct * 5;
        int kd = kk * 32 + ((l >> 4) << 3) + j;
        int c = ct * 16 + (l & 15);
        val = (kd < 129) ? w1[c * 387 + kd * 3 + tap] : 0.f;
    } else if (i < PK_W3) {                           // W2
        int r = i - PK_W2;
        int frag = r >> 9, rr = r & 511, l = rr >> 3, j = rr & 7;
        int ct = frag / 12, kk = frag - ct * 12;
        int kd = kk * 32 + ((l >> 4) << 3) + j;
        int k = kd >> 7, f = kd & 127;
        int c = ct * 16 + (l & 15);
        val = w2[c * 384 + f * 3 + k];
    } else if (i < PK_W4) {                           // W3
        int r = i - PK_W3;
        int frag = r >> 9, rr = r & 511, l = rr >> 3, j = rr & 7;
        int ct = frag / 6, kk = frag - ct * 6;
        int kd = kk * 32 + ((l >> 4) << 3) + j;
        int k = kd >> 6, f = kd & 63;
        int c = ct * 16 + (l & 15);
        val = w3[c * 192 + f * 3 + k];
    } else if (i < PK_LSTM) {                         // W4 (center tap only)
        int r = i - PK_W4;
        int frag = r >> 9, rr = r & 511, l = rr >> 3, j = rr & 7;
        int ct = frag >> 1, kk = frag & 1;
        int kd = kk * 32 + ((l >> 4) << 3) + j;
        int c = ct * 16 + (l & 15);
        val = w4[c * 192 + kd * 3 + 1];
    } else {                                          // LSTM [feat|h] -> 512 gates
        int r = i - PK_LSTM;
        int frag = r >> 9, rr = r & 511, l = rr >> 3, j = rr & 7;
        int ct = frag >> 3, kk = frag & 7;
        int kd = kk * 32 + ((l >> 4) << 3) + j;
        int n = ct * 16 + (l & 15);
        val = (kd < 128) ? wih[n * 128 + kd] : whh[n * 128 + (kd - 128)];
    }
    wp[i] = f2bf(val);
}

// ---------------- K1: STFT (MFMA) + magnitude ----------------
// 16 batches/block, 256 thr (4 waves). M=48 rows (b*3+t), N=272 (17 ct), K=256.
__global__ __launch_bounds__(256, 3) void stft_kernel(
    const float* __restrict__ x, const ushort_t* __restrict__ wp,
    ushort_t* __restrict__ magg)
{
    __shared__ ushort_t xs[48 * 264];   // im2col; later aliased as mag staging [16][480]
    __shared__ ushort_t s[48 * 264];
    const int tid = threadIdx.x, lane = tid & 63, wid = tid >> 6;
    const int l15 = lane & 15, lk = lane >> 4;

    {
        const float4* xg = (const float4*)(x + (size_t)blockIdx.x * 16 * 512);
#pragma unroll
        for (int i = 0; i < 8; ++i) {
            int idx4 = tid + i * 256;
            float4 v = xg[idx4];
            int b = idx4 >> 7, c4 = idx4 & 127;
            int si = c4 * 4, t1 = si >> 7;
            unsigned int u0 = pack2(v.x, v.y), u1 = pack2(v.z, v.w);
            if (t1 < 3) {
                ushort_t* p = &xs[(b * 3 + t1) * 264 + (si & 127)];
                *(unsigned int*)p = u0; *(unsigned int*)(p + 2) = u1;
            }
            if (t1 >= 1) {
                ushort_t* p = &xs[(b * 3 + t1 - 1) * 264 + (si & 127) + 128];
                *(unsigned int*)p = u0; *(unsigned int*)(p + 2) = u1;
            }
        }
    }
    __syncthreads();

    for (int ct = wid; ct < 17; ct += 4) {
        short8 bfrag[8];
        const short8* bp = (const short8*)(wp + PK_STFT) + (size_t)(ct * 8) * 64 + lane;
#pragma unroll
        for (int kk = 0; kk < 8; ++kk) bfrag[kk] = bp[kk * 64];
        int col = ct * 16 + l15;
#pragma unroll
        for (int rt = 0; rt < 3; ++rt) {
            const ushort_t* abase = &xs[(rt * 16 + l15) * 264 + lk * 8];
            floatx4 acc = {0.f, 0.f, 0.f, 0.f};
#pragma unroll
            for (int kk = 0; kk < 8; ++kk) {
                short8 af = *(const short8*)(abase + kk * 32);
                acc = MFMA16(af, bfrag[kk], acc);
            }
            if (col < 258) {
                int r0 = rt * 16 + lk * 4;
#pragma unroll
                for (int jj = 0; jj < 4; ++jj) s[(r0 + jj) * 264 + col] = f2bf(acc[jj]);
            }
        }
    }
    __syncthreads();

    // magnitude -> LDS staging (aliases xs), then coalesced store
    {
        ushort_t* ml = xs;                    // [16][480] linear, 7680 ushorts
        for (int idx = tid; idx < 48 * 129; idx += 256) {
            int bt = idx / 129, f = idx - bt * 129;
            float re = bf2f(s[bt * 264 + f]);
            float im = bf2f(s[bt * 264 + 129 + f]);
            int b = bt / 3, t = bt - b * 3;
            ml[b * 480 + t * 160 + f] = f2bf(sqrtf(re * re + im * im));
        }
        for (int idx = tid; idx < 48 * 31; idx += 256) {
            int bt = idx / 31, f = 129 + (idx - bt * 31);
            int b = bt / 3, t = bt - b * 3;
            ml[b * 480 + t * 160 + f] = 0;
        }
    }
    __syncthreads();
    {
        unsigned int* mgd = (unsigned int*)(magg + (size_t)blockIdx.x * 16 * 480);
        const unsigned int* mls = (const unsigned int*)xs;
#pragma unroll
        for (int k = 0; k < 15; ++k) mgd[tid + k * 256] = mls[tid + k * 256];
    }
}

// ---------------- K2: conv1..conv4 (all MFMA), 16 batches/block ----------------
__global__ __launch_bounds__(256) void conv_kernel(
    const ushort_t* __restrict__ wp, const ushort_t* __restrict__ magg,
    const float* __restrict__ b1, const float* __restrict__ b2,
    const float* __restrict__ b3, const float* __restrict__ b4,
    ushort_t* __restrict__ featg)
{
    __shared__ ushort_t big[13440];      // magp [16][5][168] -> (alias) h1h [16][5][136]
    __shared__ ushort_t h2h[16 * 3 * 72]; // h2h; later aliased as feat staging [16][128]
    __shared__ ushort_t h3s[16 * 72];
    const int tid = threadIdx.x, lane = tid & 63, wid = tid >> 6;
    const int l15 = lane & 15, lk = lane >> 4;

    // stage: halo rows t'=0,4 zero; h2h row 0 zero; mag rows t'=1..3
    {
        unsigned int* bz = (unsigned int*)big;
        for (int i = tid; i < 2688; i += 256) {
            int bb = i / 168, r = i - bb * 168;
            int tp = (r < 84) ? 0 : 4, f2 = (r < 84) ? r : r - 84;
            bz[(bb * 5 + tp) * 84 + f2] = 0u;
        }
        for (int i = tid; i < 576; i += 256) {
            int bb = i / 36, f2 = i - bb * 36;
            ((unsigned int*)h2h)[bb * 108 + f2] = 0u;
        }
        const unsigned int* mg = (const unsigned int*)(magg + (size_t)blockIdx.x * 16 * 480);
        for (int i = tid; i < 3840; i += 256) {
            int bb = i / 240, r = i - bb * 240;
            int t = r / 80, f2 = r - t * 80;
            bz[(bb * 5 + 1 + t) * 84 + f2] = mg[i];
        }
    }
    __syncthreads();

    // conv1: M=48(3rt) N=128(8ct) K=160x3taps; wave owns ct {wid, wid+4}
    floatx4 acc1[2][3];
#pragma unroll
    for (int ci = 0; ci < 2; ++ci)
#pragma unroll
        for (int rt = 0; rt < 3; ++rt) acc1[ci][rt] = (floatx4){0.f, 0.f, 0.f, 0.f};
#pragma unroll
    for (int ci = 0; ci < 2; ++ci) {
        int ct = wid + ci * 4;
        short8 bfrag[15];
#pragma unroll
        for (int tap = 0; tap < 3; ++tap)
#pragma unroll
            for (int kk = 0; kk < 5; ++kk)
                bfrag[tap * 5 + kk] = ((const short8*)(wp + PK_W1))[(size_t)(tap * 40 + ct * 5 + kk) * 64 + lane];
#pragma unroll
        for (int rt = 0; rt < 3; ++rt) {
            int obt = rt * 16 + l15;
            int b = obt / 3, t = obt - b * 3;
#pragma unroll
            for (int tap = 0; tap < 3; ++tap) {
                const ushort_t* abase = &big[(b * 5 + t + tap) * 168 + lk * 8];
#pragma unroll
                for (int kk = 0; kk < 5; ++kk) {
                    short8 af = *(const short8*)(abase + kk * 32);
                    acc1[ci][rt] = MFMA16(af, bfrag[tap * 5 + kk], acc1[ci][rt]);
                }
            }
        }
    }
    __syncthreads();

    // write h1h (aliased over magp): halo zeros + biased relu results
    {
        unsigned int* h1z = (unsigned int*)big;
        for (int i = tid; i < 2176; i += 256) {
            int bb = i / 136, r = i - bb * 136;
            int tp = (r < 68) ? 0 : 4, f2 = (r < 68) ? r : r - 68;
            h1z[(bb * 5 + tp) * 68 + f2] = 0u;
        }
#pragma unroll
        for (int ci = 0; ci < 2; ++ci) {
            int ct = wid + ci * 4;
            int col = ct * 16 + l15;
            float bias = b1[col];
#pragma unroll
            for (int rt = 0; rt < 3; ++rt)
#pragma unroll
                for (int jj = 0; jj < 4; ++jj) {
                    int obt = rt * 16 + lk * 4 + jj;
                    int b = obt / 3, t = obt - b * 3;
                    big[(b * 5 + t + 1) * 136 + col] = f2bf(fmaxf(acc1[ci][rt][jj] + bias, 0.f));
                }
        }
    }
    __syncthreads();

    // conv2: M=32(2rt) N=64(4ct) K=384(12kk); wave owns ct=wid
    {
        int ct = wid;
        short8 bfrag[12];
#pragma unroll
        for (int kk = 0; kk < 12; ++kk)
            bfrag[kk] = ((const short8*)(wp + PK_W2))[(size_t)(ct * 12 + kk) * 64 + lane];
        int col = ct * 16 + l15;
        float bias = b2[col];
#pragma unroll
        for (int rt = 0; rt < 2; ++rt) {
            floatx4 acc = {0.f, 0.f, 0.f, 0.f};
            int orow = rt * 16 + l15;
            int b = orow >> 1, t2 = orow & 1;
#pragma unroll
            for (int kk = 0; kk < 12; ++kk) {
                int k = kk >> 2, f = (kk & 3) * 32 + lk * 8;
                short8 af = *(const short8*)(&big[(b * 5 + 2 * t2 + k) * 136 + f]);
                acc = MFMA16(af, bfrag[kk], acc);
            }
#pragma unroll
            for (int jj = 0; jj < 4; ++jj) {
                int orw = rt * 16 + lk * 4 + jj;
                int bb = orw >> 1, tt = orw & 1;
                h2h[(bb * 3 + 1 + tt) * 72 + col] = f2bf(fmaxf(acc[jj] + bias, 0.f));
            }
        }
    }
    __syncthreads();

    // conv3: M=16(1rt) N=64(4ct) K=192(6kk); wave owns ct=wid
    {
        int ct = wid;
        short8 bfrag[6];
#pragma unroll
        for (int kk = 0; kk < 6; ++kk)
            bfrag[kk] = ((const short8*)(wp + PK_W3))[(size_t)(ct * 6 + kk) * 64 + lane];
        int col = ct * 16 + l15;
        float bias = b3[col];
        floatx4 acc = {0.f, 0.f, 0.f, 0.f};
        int b = l15;
#pragma unroll
        for (int kk = 0; kk < 6; ++kk) {
            int k = kk >> 1, f = (kk & 1) * 32 + lk * 8;
            short8 af = *(const short8*)(&h2h[(b * 3 + k) * 72 + f]);
            acc = MFMA16(af, bfrag[kk], acc);
        }
#pragma unroll
        for (int jj = 0; jj < 4; ++jj) {
            int bb = lk * 4 + jj;
            h3s[bb * 72 + col] = f2bf(fmaxf(acc[jj] + bias, 0.f));
        }
    }
    __syncthreads();

    // conv4: M=16(1rt) N=128(8ct) K=64(2kk); stage feat in LDS (alias h2h), coalesced store
    {
        ushort_t* fbuf = h2h;                 // [16][128], h2h reads done (barrier above)
#pragma unroll
        for (int ci = 0; ci < 2; ++ci) {
            int ct = wid + ci * 4;
            short8 bf0 = ((const short8*)(wp + PK_W4))[(size_t)(ct * 2 + 0) * 64 + lane];
            short8 bf1 = ((const short8*)(wp + PK_W4))[(size_t)(ct * 2 + 1) * 64 + lane];
            int col = ct * 16 + l15;
            float bias = b4[col];
            floatx4 acc = {0.f, 0.f, 0.f, 0.f};
            int b = l15;
            short8 a0 = *(const short8*)(&h3s[b * 72 + lk * 8]);
            short8 a1 = *(const short8*)(&h3s[b * 72 + 32 + lk * 8]);
            acc = MFMA16(a0, bf0, acc);
            acc = MFMA16(a1, bf1, acc);
#pragma unroll
            for (int jj = 0; jj < 4; ++jj) {
                int bb = lk * 4 + jj;
                fbuf[bb * 128 + col] = f2bf(fmaxf(acc[jj] + bias, 0.f));
            }
        }
        __syncthreads();
        unsigned int* fgd = (unsigned int*)(featg + (size_t)blockIdx.x * 16 * 128);
        const unsigned int* fls = (const unsigned int*)fbuf;
#pragma unroll
        for (int k = 0; k < 4; ++k) fgd[tid + k * 256] = fls[tid + k * 256];
    }
}

// ---------------- K3: LSTM gates (MFMA) + cell + head (round-3 version) ----------------
// 32 batches/block, 512 thr (8 waves). M=32(2rt) N=512(32ct) K=256(8kk).
// Wave w owns cts {w, w+8, w+16, w+24}: i/f/g/o columns for cc=w*16+l15 land in the same lane.
__global__ __launch_bounds__(512) void lstm_kernel(
    const ushort_t* __restrict__ featg, const float* __restrict__ state,
    const ushort_t* __restrict__ wp, const float* __restrict__ bih,
    const float* __restrict__ bhh, const float* __restrict__ fw,
    const float* __restrict__ fbp, float* __restrict__ out, int B)
{
    __shared__ ushort_t inc[32 * 264];   // cols 0..127 feat, 128..255 h_prev
    __shared__ float red[256];
    const int tid = threadIdx.x, lane = tid & 63, wid = tid >> 6;
    const int l15 = lane & 15, lk = lane >> 4;
    const size_t b0 = (size_t)blockIdx.x * 32;
    const int cc = wid * 16 + l15;

    // prefetch c_prev (consumed after MFMA; latency hides under it)
    const float* cprev = state + (size_t)B * 128;
    float cpv[2][4];
#pragma unroll
    for (int rt = 0; rt < 2; ++rt)
#pragma unroll
        for (int jj = 0; jj < 4; ++jj)
            cpv[rt][jj] = cprev[(b0 + rt * 16 + lk * 4 + jj) * 128 + cc];

    {
        const unsigned int* fg = (const unsigned int*)(featg + b0 * 128);
        unsigned int* ip = (unsigned int*)inc;
        for (int i = tid; i < 2048; i += 512) {
            int bb = i >> 6, f2 = i & 63;
            ip[bb * 132 + f2] = fg[i];
        }
        const float2* hp2 = (const float2*)(state + b0 * 128);
        for (int i = tid; i < 2048; i += 512) {
            int bb = i >> 6, c2 = i & 63;
            float2 v = hp2[i];
            ip[bb * 132 + 64 + c2] = pack2(v.x, v.y);
        }
    }
    __syncthreads();

    floatx4 acc[4][2];
#pragma unroll
    for (int ci = 0; ci < 4; ++ci) {
        int ct = wid + ci * 8;
        short8 bfrag[8];
#pragma unroll
        for (int kk = 0; kk < 8; ++kk)
            bfrag[kk] = ((const short8*)(wp + PK_LSTM))[(size_t)(ct * 8 + kk) * 64 + lane];
#pragma unroll
        for (int rt = 0; rt < 2; ++rt) {
            const ushort_t* abase = &inc[(rt * 16 + l15) * 264 + lk * 8];
            floatx4 a = {0.f, 0.f, 0.f, 0.f};
#pragma unroll
            for (int kk = 0; kk < 8; ++kk) {
                short8 af = *(const short8*)(abase + kk * 32);
                a = MFMA16(af, bfrag[kk], a);
            }
            acc[ci][rt] = a;
        }
    }

    // cell update + head partials (gates all in regs)
    float* outh = out + B;
    float* outc = out + B + (size_t)B * 128;
    float ph[2][4];
    const float bi = bih[cc] + bhh[cc];
    const float bf_ = bih[cc + 128] + bhh[cc + 128];
    const float bg = bih[cc + 256] + bhh[cc + 256];
    const float bo = bih[cc + 384] + bhh[cc + 384];
    const float fwv = fw[cc];
#pragma unroll
    for (int rt = 0; rt < 2; ++rt)
#pragma unroll
        for (int jj = 0; jj < 4; ++jj) {
            int row = rt * 16 + lk * 4 + jj;
            size_t gb = b0 + row;
            float gi = acc[0][rt][jj] + bi;
            float gf = acc[1][rt][jj] + bf_;
            float gg = acc[2][rt][jj] + bg;
            float go = acc[3][rt][jj] + bo;
            float cn = fsig(gf) * cpv[rt][jj] + fsig(gi) * ftanh(gg);
            float hn = fsig(go) * ftanh(cn);
            outh[gb * 128 + cc] = hn;
            outc[gb * 128 + cc] = cn;
            ph[rt][jj] = fmaxf(hn, 0.f) * fwv;
        }

    // head: reduce the 16 cc-lanes of each l-group, stash per (wave,row)
#pragma unroll
    for (int rt = 0; rt < 2; ++rt)
#pragma unroll
        for (int jj = 0; jj < 4; ++jj) {
            float v = ph[rt][jj];
            v += __shfl_xor(v, 1, 64);
            v += __shfl_xor(v, 2, 64);
            v += __shfl_xor(v, 4, 64);
            v += __shfl_xor(v, 8, 64);
            if (l15 == 0) red[wid * 32 + rt * 16 + lk * 4 + jj] = v;
        }
    __syncthreads();
    if (tid < 32) {
        float v = 0.f;
#pragma unroll
        for (int w = 0; w < 8; ++w) v += red[w * 32 + tid];
        out[b0 + tid] = fsig(v + fbp[0]);
    }
}

extern "C" void kernel_launch(void* const* d_in, const int* in_sizes, int n_in,
                              void* d_out, int out_size, void* d_ws, size_t ws_size,
                              hipStream_t stream) {
    const float* x      = (const float*)d_in[0];
    const float* state  = (const float*)d_in[1];
    const float* stft_w = (const float*)d_in[2];
    const float* w1     = (const float*)d_in[3];
    const float* b1     = (const float*)d_in[4];
    const float* w2     = (const float*)d_in[5];
    const float* b2     = (const float*)d_in[6];
    const float* w3     = (const float*)d_in[7];
    const float* b3     = (const float*)d_in[8];
    const float* w4     = (const float*)d_in[9];
    const float* b4     = (const float*)d_in[10];
    const float* wih    = (const float*)d_in[11];
    const float* whh    = (const float*)d_in[12];
    const float* bih    = (const float*)d_in[13];
    const float* bhh    = (const float*)d_in[14];
    const float* fw     = (const float*)d_in[15];
    const float* fbp    = (const float*)d_in[16];

    ushort_t* wp = (ushort_t*)d_ws;
    const int B = in_sizes[0] / 512;   // 16384

    prep_kernel<<<1200, 256, 0, stream>>>(stft_w, w1, w2, w3, w4, wih, whh, wp);
    stft_kernel<<<B / 16, 256, 0, stream>>>(x, wp, wp + OFF_MAG);
    conv_kernel<<<B / 16, 256, 0, stream>>>(wp, wp + OFF_MAG, b1, b2, b3, b4, wp + OFF_FEAT);
    lstm_kernel<<<B / 32, 512, 0, stream>>>(wp + OFF_FEAT, state, wp, bih, bhh, fw, fbp,
                                            (float*)d_out, B);
}